// Round 17
// baseline (541.597 us; speedup 1.0000x reference)
//
#include <hip/hip_runtime.h>
#include <cstdint>

#define B_ 4096
#define N_ 64
#define K_ 48
#define D_ 64
#define F_ 4096
#define E_ 8
#define H_ 1024
#define O_ 512
#define T_ 2
#define TH_ 256
#define NSLOT (B_ * 2)

#define MAXT1 72    // sum over e of ceil(Me/128) <= 64+7
#define MAXT2 136   // sum over e of ceil(Me/64)  <= 128+8

typedef float f32x4 __attribute__((ext_vector_type(4)));
typedef __bf16 bf16x8 __attribute__((ext_vector_type(8)));

__device__ __forceinline__ unsigned short f2bf(float f) {
    union { float f; unsigned int u; } v; v.f = f;
    unsigned int u = v.u;
    u += 0x7FFFu + ((u >> 16) & 1u);   // RNE
    return (unsigned short)(u >> 16);
}

__device__ __forceinline__ void gload_lds16(const void* gptr, void* lptr) {
    auto* g = reinterpret_cast<const __attribute__((address_space(1))) unsigned int*>(
        reinterpret_cast<uintptr_t>(gptr));
    auto* l = reinterpret_cast<__attribute__((address_space(3))) unsigned int*>(
        reinterpret_cast<uintptr_t>(lptr));
    __builtin_amdgcn_global_load_lds(g, l, 16, 0, 0);
}

// ---------------- 0. prefix sums of embW over k, bias folded in ----------------
__global__ __launch_bounds__(64) void prefix_kernel(
    const float* __restrict__ embW, const float* __restrict__ embB,
    float* __restrict__ P)
{
    int n = blockIdx.x;
    int lane = threadIdx.x;
    float acc = embB[n * D_ + lane];
    const float* wsrc = embW + (size_t)n * K_ * D_ + lane;
    float* dst = P + (size_t)n * K_ * D_ + lane;
    #pragma unroll 8
    for (int k = 0; k < K_; ++k) {
        dst[k * D_] = acc;
        acc += wsrc[k * D_];
    }
}

// ---------------- 1. PLE + embedding + gate logits ----------------
__global__ __launch_bounds__(256) void ple_embed_kernel(
    const float* __restrict__ x, const float* __restrict__ plw,
    const float* __restrict__ plb, const float* __restrict__ embW,
    const float* __restrict__ P, const float* __restrict__ gateW,
    unsigned short* __restrict__ flat_bf, float* __restrict__ logits)
{
    __shared__ float gpart[4][E_];
    int b = blockIdx.x;
    int tid = threadIdx.x, lane = tid & 63, w = tid >> 6;

    float xl = x[b * N_ + lane];
    float gp[E_];
    #pragma unroll
    for (int e = 0; e < E_; ++e) gp[e] = 0.0f;

    #pragma unroll 4
    for (int i = 0; i < 16; ++i) {
        int n = w * 16 + i;
        float xn = __shfl(xl, n);
        const float* pw = plw + n * K_;
        const float* pb = plb + n * K_;
        float t = fmaf(pw[0], xn, pb[0]);          // = K*x
        int j = (int)t;
        j = max(0, min(K_ - 1, j));
        float f = fminf(fmaxf(fmaf(pw[j], xn, pb[j]), 0.0f), 1.0f);
        size_t base = ((size_t)n * K_ + j) * D_ + lane;
        float emb = fmaxf(fmaf(f, embW[base], P[base]), 0.0f);
        flat_bf[(size_t)b * F_ + n * D_ + lane] = f2bf(emb);

        const float4* gw4 = (const float4*)(gateW + (size_t)(n * D_ + lane) * E_);
        float4 g0 = gw4[0], g1 = gw4[1];
        gp[0] = fmaf(emb, g0.x, gp[0]);
        gp[1] = fmaf(emb, g0.y, gp[1]);
        gp[2] = fmaf(emb, g0.z, gp[2]);
        gp[3] = fmaf(emb, g0.w, gp[3]);
        gp[4] = fmaf(emb, g1.x, gp[4]);
        gp[5] = fmaf(emb, g1.y, gp[5]);
        gp[6] = fmaf(emb, g1.z, gp[6]);
        gp[7] = fmaf(emb, g1.w, gp[7]);
    }

    #pragma unroll
    for (int off = 32; off > 0; off >>= 1) {
        #pragma unroll
        for (int e = 0; e < E_; ++e) gp[e] += __shfl_down(gp[e], off);
    }
    if (lane == 0) {
        #pragma unroll
        for (int e = 0; e < E_; ++e) gpart[w][e] = gp[e];
    }
    __syncthreads();
    if (tid < E_)
        logits[b * E_ + tid] =
            gpart[0][tid] + gpart[1][tid] + gpart[2][tid] + gpart[3][tid];
}

// ---------------- 2. top-2 gating ----------------
__global__ __launch_bounds__(256) void gate_top2_kernel(
    const float* __restrict__ logits, const float* __restrict__ gate_b,
    int* __restrict__ topi, float* __restrict__ topg, int* __restrict__ counts)
{
    int b = blockIdx.x * 256 + threadIdx.x;
    int lane = threadIdx.x & 63;
    float l[E_];
    #pragma unroll
    for (int e = 0; e < E_; ++e) l[e] = logits[b * E_ + e] + gate_b[e];
    int e1 = 0; float v1 = l[0];
    #pragma unroll
    for (int e = 1; e < E_; ++e) if (l[e] > v1) { v1 = l[e]; e1 = e; }
    int e2 = -1; float v2 = -1e30f;
    #pragma unroll
    for (int e = 0; e < E_; ++e) if (e != e1 && l[e] > v2) { v2 = l[e]; e2 = e; }
    float ex = expf(v2 - v1);
    float g1 = 1.0f / (1.0f + ex);
    float g2 = ex / (1.0f + ex);
    topi[b * 2] = e1; topi[b * 2 + 1] = e2;
    topg[b * 2] = g1; topg[b * 2 + 1] = g2;
    #pragma unroll
    for (int e = 0; e < E_; ++e) {
        unsigned long long m1 = __ballot(e1 == e);
        unsigned long long m2 = __ballot(e2 == e);
        if (lane == 0) {
            int c = __popcll(m1) + __popcll(m2);
            if (c) atomicAdd(&counts[e], c);
        }
    }
}

// ---------------- 3. scan + tile tables (BM=128 for fc1, BM=64 for fc2) --------
__global__ void scan_kernel(const int* __restrict__ counts, int* __restrict__ offsets,
                            int* __restrict__ tiles1, int* __restrict__ tiles2,
                            int* __restrict__ ntiles) {
    int e = threadIdx.x;
    if (e >= E_) return;
    int c[E_];
    #pragma unroll
    for (int i = 0; i < E_; ++i) c[i] = counts[i];
    int off = 0, tb = 0, tb2 = 0, tot = 0, ttot = 0, ttot2 = 0;
    #pragma unroll
    for (int i = 0; i < E_; ++i) {
        int t = (c[i] + 127) >> 7;
        int t2 = (c[i] + 63) >> 6;
        if (i < e) { off += c[i]; tb += t; tb2 += t2; }
        tot += c[i]; ttot += t; ttot2 += t2;
    }
    offsets[e] = off;
    if (e == 0) { offsets[E_] = tot; ntiles[0] = ttot; ntiles[1] = ttot2; }
    int nt = (c[e] + 127) >> 7;
    for (int tr = 0; tr < nt; ++tr) tiles1[tb + tr] = (e << 16) | tr;
    int nt2 = (c[e] + 63) >> 6;
    for (int tr = 0; tr < nt2; ++tr) tiles2[tb2 + tr] = (e << 16) | tr;
}

// ---------------- 4. scatter samples into per-expert slot lists ----------------
// Also records slots[b*2+j] so the combine kernel can gather without atomics.
__global__ __launch_bounds__(256) void scatter_kernel(
    const int* __restrict__ topi, const float* __restrict__ topg,
    const int* __restrict__ offsets, int* __restrict__ cursors,
    int* __restrict__ rows, float* __restrict__ gatev, int* __restrict__ slots)
{
    int b = blockIdx.x * 256 + threadIdx.x;
    int lane = threadIdx.x & 63;
    #pragma unroll
    for (int j = 0; j < 2; ++j) {
        int e = topi[b * 2 + j];
        float g = topg[b * 2 + j];
        #pragma unroll
        for (int ex = 0; ex < E_; ++ex) {
            unsigned long long m = __ballot(e == ex);
            if (e == ex) {
                int leader = __builtin_ctzll(m);
                int base = 0;
                if (lane == leader) base = atomicAdd(&cursors[ex], __popcll(m));
                base = __shfl(base, leader);
                int pos = base + __popcll(m & ((1ull << lane) - 1ull));
                int slot = offsets[ex] + pos;
                rows[slot] = b;
                gatev[slot] = g;
                slots[b * 2 + j] = slot;
            }
        }
    }
}

// ---------------- 5. weights -> MFMA-fragment order, f32 -> bf16 ----------------
// in: (E, R, C) f32 (R = K dim, C = output-col dim)
// out: [e][n0 = C/16][k0 = R/32][lane][8] bf16; a wave's B-fragment load is
// one coalesced 1 KB global_load_dwordx4 (lane-contiguous 16B each).
// Fragment element j of lane: (k = k0*32 + (lane>>4)*8 + j, n = n0*16 + (lane&15)).
__global__ __launch_bounds__(256) void wfrag_kernel(
    const float* __restrict__ in, unsigned short* __restrict__ out, int R, int C)
{
    __shared__ float tile[64][65];
    int e = blockIdx.z;
    int rb = blockIdx.x, cb = blockIdx.y;
    const float* src = in + (size_t)e * R * C + (size_t)(rb * 64) * C + cb * 64;
    int lane = threadIdx.x & 63, w = threadIdx.x >> 6;
    #pragma unroll
    for (int i = 0; i < 16; ++i) {
        int r = w * 16 + i;
        tile[r][lane] = src[(size_t)r * C + lane];
    }
    __syncthreads();
    int NB = C >> 4, KB = R >> 5;
    #pragma unroll
    for (int it = 0; it < 2; ++it) {
        int t = threadIdx.x + it * 256;
        int n0r = t >> 7, k0r = (t >> 6) & 1, ln = t & 63;
        int q = ln >> 4, nl = ln & 15;
        unsigned short v[8];
        #pragma unroll
        for (int j = 0; j < 8; ++j)
            v[j] = f2bf(tile[k0r * 32 + q * 8 + j][n0r * 16 + nl]);
        size_t didx = (((size_t)e * NB + cb * 4 + n0r) * KB + rb * 2 + k0r) * 512
                      + (size_t)ln * 8;
        uint4 pk;
        pk.x = v[0] | ((unsigned)v[1] << 16);
        pk.y = v[2] | ((unsigned)v[3] << 16);
        pk.z = v[4] | ((unsigned)v[5] << 16);
        pk.w = v[6] | ((unsigned)v[7] << 16);
        *(uint4*)&out[didx] = pk;
    }
}

// ---------------- 6. FC1: 128x64 + pipeline + XCD colocation + counted vmcnt ----
__global__ __launch_bounds__(256) void fc1_kernel(
    const unsigned short* __restrict__ Abf,   // flat_bf (B,F)
    const unsigned short* __restrict__ Wf,    // frag layout (E, H/16, F/32, 64, 8)
    const float* __restrict__ bias,           // (E,H)
    const int* __restrict__ rows, const int* __restrict__ offsets,
    const int* __restrict__ tiles1, const int* __restrict__ ntiles,
    unsigned short* __restrict__ Hbf)         // (NSLOT,H) bf16
{
    // bijective decode: bid = tlow + 8*(cn + 16*tgrp); tile = tgrp*8 + tlow
    int bid = blockIdx.x;
    int tlow = bid & 7;
    int rest = bid >> 3;
    int cn   = rest & 15;
    int tile = (rest >> 4) * 8 + tlow;
    if (tile >= ntiles[0]) return;
    int te = tiles1[tile];
    int e = te >> 16, tr = te & 0xffff;
    int m0 = offsets[e], mEnd = offsets[e + 1];
    int Me = mEnd - m0;

    __shared__ alignas(16) unsigned short As[2][128 * 64];   // 32 KB

    int tid = threadIdx.x, lane = tid & 63, wv = tid >> 6;
    int lr = lane >> 3;
    int cg = (lane & 7) ^ lr;     // XOR swizzle -> 2-way-only bank aliasing

    const unsigned short* aptr[4];
    #pragma unroll
    for (int i = 0; i < 4; ++i) {
        int rowA = (wv * 4 + i) * 8 + lr;
        int slot = min(m0 + tr * 128 + rowA, mEnd - 1);
        aptr[i] = Abf + (size_t)rows[slot] * F_ + cg * 8;
    }

    int wvM = wv >> 1, wvN = wv & 1;
    int m16 = lane & 15, q = lane >> 4;

    const unsigned short* bbase[2];
    #pragma unroll
    for (int nt = 0; nt < 2; ++nt) {
        int n0 = cn * 4 + wvN * 2 + nt;
        bbase[nt] = Wf + (((size_t)e * (H_ / 16) + n0) * (F_ / 32)) * 512
                    + (size_t)lane * 8;
    }

    f32x4 zero = {0.f, 0.f, 0.f, 0.f};
    f32x4 acc[4][2];
    #pragma unroll
    for (int i = 0; i < 4; ++i)
        #pragma unroll
        for (int j = 0; j < 2; ++j) acc[i][j] = zero;

#define FC_STAGE(BUF, KK) do {                                              \
    _Pragma("unroll")                                                       \
    for (int i_ = 0; i_ < 4; ++i_)                                          \
        gload_lds16(aptr[i_] + (KK), &As[BUF][(wv * 4 + i_) * 512]);        \
} while (0)

#define FC_LOADB(DST, KK) do {                                              \
    _Pragma("unroll")                                                       \
    for (int nt_ = 0; nt_ < 2; ++nt_)                                       \
        _Pragma("unroll")                                                   \
        for (int ks_ = 0; ks_ < 2; ++ks_)                                   \
            DST[nt_][ks_] = *(const bf16x8*)(bbase[nt_]                     \
                + (size_t)(KK) * 16 + ks_ * 512);                           \
} while (0)

#define FC_COMPUTE(BUF, BF) do {                                            \
    _Pragma("unroll")                                                       \
    for (int ks_ = 0; ks_ < 2; ++ks_) {                                     \
        bf16x8 af_[4];                                                      \
        _Pragma("unroll")                                                   \
        for (int mt_ = 0; mt_ < 4; ++mt_) {                                 \
            int m_ = wvM * 64 + mt_ * 16 + m16;                             \
            int pos_ = (ks_ * 4 + q) ^ (m_ & 7);                            \
            af_[mt_] = *(const bf16x8*)&As[BUF][m_ * 64 + pos_ * 8];        \
        }                                                                   \
        _Pragma("unroll")                                                   \
        for (int mt_ = 0; mt_ < 4; ++mt_)                                   \
            _Pragma("unroll")                                               \
            for (int nt_ = 0; nt_ < 2; ++nt_)                               \
                acc[mt_][nt_] = __builtin_amdgcn_mfma_f32_16x16x32_bf16(    \
                    af_[mt_], BF[nt_][ks_], acc[mt_][nt_], 0, 0, 0);        \
    }                                                                       \
} while (0)

#define FC_WAIT8() asm volatile("s_waitcnt vmcnt(8)" ::: "memory")
#define FC_WAIT0() asm volatile("s_waitcnt vmcnt(0)" ::: "memory")
#define FC_BAR()   __builtin_amdgcn_s_barrier()

    bf16x8 bA[2][2], bB[2][2];
    FC_STAGE(0, 0);
    FC_LOADB(bA, 0);                        // 8 ops in flight

    for (int k0 = 0; k0 < F_; k0 += 128) {
        FC_STAGE(1, k0 + 64);               // +8 -> 16 in flight
        FC_LOADB(bB, k0 + 64);
        FC_WAIT8();                         // oldest 8 done: As[0] written, bA ready
        FC_BAR();                           // all waves' As[0] writes visible
        FC_COMPUTE(0, bA);
        FC_BAR();                           // all reads of As[0] done -> safe to restage

        if (k0 + 128 < F_) {
            FC_STAGE(0, k0 + 128);          // +8 -> 16 in flight
            FC_LOADB(bA, k0 + 128);
            FC_WAIT8();                     // oldest 8 done: As[1] written, bB ready
        } else {
            FC_WAIT0();                     // tail: nothing new issued, drain all
        }
        FC_BAR();
        FC_COMPUTE(1, bB);
        FC_BAR();
    }

    #pragma unroll
    for (int nt = 0; nt < 2; ++nt) {
        int col = cn * 64 + wvN * 32 + nt * 16 + m16;
        float bv = bias[e * H_ + col];
        #pragma unroll
        for (int mt = 0; mt < 4; ++mt) {
            int rbase = tr * 128 + wvM * 64 + mt * 16 + q * 4;
            #pragma unroll
            for (int r = 0; r < 4; ++r) {
                int rr = rbase + r;
                if (rr < Me) {
                    float v = fmaxf(acc[mt][nt][r] + bv, 0.0f);
                    Hbf[(size_t)(m0 + rr) * H_ + col] = f2bf(v);
                }
            }
        }
    }
}

// ---------------- 7. FC2: BM=64 tile (2x grid -> 4.3 blocks/CU), atomic-free ----
// Same counted-vmcnt pipeline as fc1, recounted for 6 VMEM ops/phase
// (2 gload_lds + 4 B-frag). acc[2][2], 16 KB LDS. tiles2 table (BM=64).
__global__ __launch_bounds__(256) void fc2_kernel(
    const unsigned short* __restrict__ Hbf,   // (NSLOT,H) bf16
    const unsigned short* __restrict__ Wf,    // frag layout (E, O/16, H/32, 64, 8)
    const float* __restrict__ bias,           // (E,O)
    const int* __restrict__ offsets, const int* __restrict__ tiles2,
    const int* __restrict__ ntiles, float* __restrict__ eo)   // (NSLOT,O) f32
{
    // bijective decode: bid = tlow + 8*(cn + 8*tgrp); tile = tgrp*8 + tlow
    int bid = blockIdx.x;
    int tlow = bid & 7;
    int rest = bid >> 3;
    int cn   = rest & 7;
    int tile = (rest >> 3) * 8 + tlow;
    if (tile >= ntiles[1]) return;
    int te = tiles2[tile];
    int e = te >> 16, tr = te & 0xffff;
    int m0 = offsets[e], mEnd = offsets[e + 1];
    int Me = mEnd - m0;

    __shared__ alignas(16) unsigned short As[2][64 * 64];   // 16 KB

    int tid = threadIdx.x, lane = tid & 63, wv = tid >> 6;
    int lr = lane >> 3;
    int cg = (lane & 7) ^ lr;

    const unsigned short* aptr[2];
    #pragma unroll
    for (int i = 0; i < 2; ++i) {
        int rowA = (wv * 2 + i) * 8 + lr;     // rows [wv*16, wv*16+16)
        int slot = min(m0 + tr * 64 + rowA, mEnd - 1);
        aptr[i] = Hbf + (size_t)slot * H_ + cg * 8;
    }

    int wvM = wv >> 1, wvN = wv & 1;
    int m16 = lane & 15, q = lane >> 4;

    const unsigned short* bbase[2];
    #pragma unroll
    for (int nt = 0; nt < 2; ++nt) {
        int n0 = cn * 4 + wvN * 2 + nt;
        bbase[nt] = Wf + (((size_t)e * (O_ / 16) + n0) * (H_ / 32)) * 512
                    + (size_t)lane * 8;
    }

    f32x4 zero = {0.f, 0.f, 0.f, 0.f};
    f32x4 acc[2][2];
    #pragma unroll
    for (int i = 0; i < 2; ++i)
        #pragma unroll
        for (int j = 0; j < 2; ++j) acc[i][j] = zero;

#define FC2_STAGE(BUF, KK) do {                                             \
    _Pragma("unroll")                                                       \
    for (int i_ = 0; i_ < 2; ++i_)                                          \
        gload_lds16(aptr[i_] + (KK), &As[BUF][(wv * 2 + i_) * 512]);        \
} while (0)

#define FC2_COMPUTE(BUF, BF) do {                                           \
    _Pragma("unroll")                                                       \
    for (int ks_ = 0; ks_ < 2; ++ks_) {                                     \
        bf16x8 af_[2];                                                      \
        _Pragma("unroll")                                                   \
        for (int mt_ = 0; mt_ < 2; ++mt_) {                                 \
            int m_ = wvM * 32 + mt_ * 16 + m16;                             \
            int pos_ = (ks_ * 4 + q) ^ (m_ & 7);                            \
            af_[mt_] = *(const bf16x8*)&As[BUF][m_ * 64 + pos_ * 8];        \
        }                                                                   \
        _Pragma("unroll")                                                   \
        for (int mt_ = 0; mt_ < 2; ++mt_)                                   \
            _Pragma("unroll")                                               \
            for (int nt_ = 0; nt_ < 2; ++nt_)                               \
                acc[mt_][nt_] = __builtin_amdgcn_mfma_f32_16x16x32_bf16(    \
                    af_[mt_], BF[nt_][ks_], acc[mt_][nt_], 0, 0, 0);        \
    }                                                                       \
} while (0)

#define FC2_WAIT6() asm volatile("s_waitcnt vmcnt(6)" ::: "memory")

    bf16x8 bA[2][2], bB[2][2];
    FC2_STAGE(0, 0);
    FC_LOADB(bA, 0);                        // 6 ops in flight

    for (int k0 = 0; k0 < H_; k0 += 128) {
        FC2_STAGE(1, k0 + 64);              // +6 -> 12 in flight
        FC_LOADB(bB, k0 + 64);
        FC2_WAIT6();                        // oldest 6 done: As[0] + bA ready
        FC_BAR();
        FC2_COMPUTE(0, bA);
        FC_BAR();

        if (k0 + 128 < H_) {
            FC2_STAGE(0, k0 + 128);
            FC_LOADB(bA, k0 + 128);
            FC2_WAIT6();
        } else {
            FC_WAIT0();
        }
        FC_BAR();
        FC2_COMPUTE(1, bB);
        FC_BAR();
    }

    #pragma unroll
    for (int nt = 0; nt < 2; ++nt) {
        int col = cn * 64 + wvN * 32 + nt * 16 + m16;
        float bv = bias[e * O_ + col];
        #pragma unroll
        for (int mt = 0; mt < 2; ++mt) {
            int rbase = tr * 64 + wvM * 32 + mt * 16 + q * 4;
            #pragma unroll
            for (int r = 0; r < 4; ++r) {
                int rr = rbase + r;
                if (rr < Me) {
                    eo[(size_t)(m0 + rr) * O_ + col] = acc[mt][nt][r] + bv;
                }
            }
        }
    }
}

#undef FC_STAGE
#undef FC_LOADB
#undef FC_COMPUTE
#undef FC_WAIT8
#undef FC_WAIT0
#undef FC_BAR
#undef FC2_STAGE
#undef FC2_COMPUTE
#undef FC2_WAIT6

// ---------------- 7b. gated combine: moe[b] = g0*eo[s0] + g1*eo[s1] -------------
__global__ __launch_bounds__(256) void moe_combine_kernel(
    const float* __restrict__ eo, const int* __restrict__ slots,
    const float* __restrict__ gatev, float* __restrict__ moe)
{
    int gid = blockIdx.x * 256 + threadIdx.x;
    int b = gid >> 7;                 // O_/4 = 128 threads per sample
    int c = (gid & 127) * 4;
    int s0 = slots[b * 2];
    int s1 = slots[b * 2 + 1];
    float g0 = gatev[s0];
    float g1 = gatev[s1];
    float4 v0 = *(const float4*)&eo[(size_t)s0 * O_ + c];
    float4 v1 = *(const float4*)&eo[(size_t)s1 * O_ + c];
    float4 r;
    r.x = g0 * v0.x + g1 * v1.x;
    r.y = g0 * v0.y + g1 * v1.y;
    r.z = g0 * v0.z + g1 * v1.z;
    r.w = g0 * v0.w + g1 * v1.w;
    *(float4*)&moe[(size_t)b * O_ + c] = r;
}

// ---------------- 8. fused towers ----------------
__global__ __launch_bounds__(256) void tower_kernel(
    const float* __restrict__ moe, const float* __restrict__ tw1,
    const float* __restrict__ tb1, const float* __restrict__ tw2,
    const float* __restrict__ tb2, float* __restrict__ out)
{
    __shared__ float ms[8 * O_];       // 16 KB
    __shared__ float red[16][4];
    int b0 = blockIdx.x * 8;
    int tid = threadIdx.x, lane = tid & 63, wv = tid >> 6;
    for (int idx = tid; idx < 8 * O_; idx += 256)
        ms[idx] = moe[(size_t)b0 * O_ + idx];
    __syncthreads();

    int s = tid;
    float a0[8], a1[8];
    float bv0 = tb1[s], bv1 = tb1[TH_ + s];
    #pragma unroll
    for (int i = 0; i < 8; ++i) { a0[i] = bv0; a1[i] = bv1; }

    for (int o = 0; o < O_; o += 4) {
        float w0[4], w1[4];
        #pragma unroll
        for (int u = 0; u < 4; ++u) {
            w0[u] = tw1[(size_t)(o + u) * TH_ + s];
            w1[u] = tw1[(size_t)(O_ + o + u) * TH_ + s];
        }
        #pragma unroll
        for (int i = 0; i < 8; ++i) {
            float4 mv = *(const float4*)&ms[i * O_ + o];
            a0[i] = fmaf(mv.x, w0[0], a0[i]);
            a0[i] = fmaf(mv.y, w0[1], a0[i]);
            a0[i] = fmaf(mv.z, w0[2], a0[i]);
            a0[i] = fmaf(mv.w, w0[3], a0[i]);
            a1[i] = fmaf(mv.x, w1[0], a1[i]);
            a1[i] = fmaf(mv.y, w1[1], a1[i]);
            a1[i] = fmaf(mv.z, w1[2], a1[i]);
            a1[i] = fmaf(mv.w, w1[3], a1[i]);
        }
    }

    float w2a = tw2[s], w2b = tw2[TH_ + s];
    #pragma unroll
    for (int i = 0; i < 8; ++i) {
        float p0 = fmaxf(a0[i], 0.0f) * w2a;
        float p1 = fmaxf(a1[i], 0.0f) * w2b;
        #pragma unroll
        for (int off = 32; off > 0; off >>= 1) {
            p0 += __shfl_down(p0, off);
            p1 += __shfl_down(p1, off);
        }
        if (lane == 0) { red[i * 2 + 0][wv] = p0; red[i * 2 + 1][wv] = p1; }
    }
    __syncthreads();
    if (tid < 16) {
        int i = tid >> 1, t = tid & 1;
        float v = red[tid][0] + red[tid][1] + red[tid][2] + red[tid][3] + tb2[t];
        out[(size_t)(b0 + i) * T_ + t] = v;
    }
}

extern "C" void kernel_launch(void* const* d_in, const int* in_sizes, int n_in,
                              void* d_out, int out_size, void* d_ws, size_t ws_size,
                              hipStream_t stream)
{
    const float* x     = (const float*)d_in[0];
    const float* plw   = (const float*)d_in[1];
    const float* plb   = (const float*)d_in[2];
    const float* embW  = (const float*)d_in[3];
    const float* embB  = (const float*)d_in[4];
    const float* gateW = (const float*)d_in[5];
    const float* gateB = (const float*)d_in[6];
    const float* eW1   = (const float*)d_in[7];
    const float* eB1   = (const float*)d_in[8];
    const float* eW2   = (const float*)d_in[9];
    const float* eB2   = (const float*)d_in[10];
    const float* tw1   = (const float*)d_in[11];
    const float* tb1   = (const float*)d_in[12];
    const float* tw2   = (const float*)d_in[13];
    const float* tb2   = (const float*)d_in[14];
    float* out = (float*)d_out;

    char* w = (char*)d_ws;
    auto alloc = [&](size_t bytes) {
        char* p = w; w += (bytes + 255) & ~(size_t)255; return p;
    };
    unsigned short* flat_bf = (unsigned short*)alloc((size_t)B_ * F_ * 2);      // 33.6 MB
    unsigned short* W1f     = (unsigned short*)alloc((size_t)E_ * H_ * F_ * 2); // 67.1 MB
    unsigned short* W2f     = (unsigned short*)alloc((size_t)E_ * O_ * H_ * 2); //  8.4 MB
    unsigned short* Hbf     = (unsigned short*)alloc((size_t)NSLOT * H_ * 2);   // 16.8 MB
    float* eo      = (float*)alloc((size_t)NSLOT * O_ * 4);                     // 16.8 MB
    float* Ppre    = (float*)alloc((size_t)N_ * K_ * D_ * 4);                   // 786 KB
    float* logits  = (float*)alloc((size_t)B_ * E_ * 4);
    float* moe     = (float*)alloc((size_t)B_ * O_ * 4);                        //  8.4 MB
    int*   topi    = (int*)alloc((size_t)B_ * 2 * 4);
    float* topg    = (float*)alloc((size_t)B_ * 2 * 4);
    int*   rows    = (int*)alloc((size_t)NSLOT * 4);
    float* gatev   = (float*)alloc((size_t)NSLOT * 4);
    int*   slots   = (int*)alloc((size_t)B_ * 2 * 4);
    int*   counts  = (int*)alloc(E_ * 4);
    int*   offsets = (int*)alloc((E_ + 1) * 4);
    int*   cursors = (int*)alloc(E_ * 4);
    int*   tiles1  = (int*)alloc(MAXT1 * 4);
    int*   tiles2  = (int*)alloc(MAXT2 * 4);
    int*   ntiles  = (int*)alloc(2 * 4);

    hipMemsetAsync(counts, 0, E_ * 4, stream);
    hipMemsetAsync(cursors, 0, E_ * 4, stream);

    prefix_kernel<<<N_, 64, 0, stream>>>(embW, embB, Ppre);
    ple_embed_kernel<<<B_, 256, 0, stream>>>(x, plw, plb, embW, Ppre, gateW,
                                             flat_bf, logits);
    wfrag_kernel<<<dim3(F_ / 64, H_ / 64, E_), 256, 0, stream>>>(eW1, W1f, F_, H_);
    wfrag_kernel<<<dim3(H_ / 64, O_ / 64, E_), 256, 0, stream>>>(eW2, W2f, H_, O_);
    gate_top2_kernel<<<B_ / 256, 256, 0, stream>>>(logits, gateB, topi, topg, counts);
    scan_kernel<<<1, 64, 0, stream>>>(counts, offsets, tiles1, tiles2, ntiles);
    scatter_kernel<<<B_ / 256, 256, 0, stream>>>(topi, topg, offsets, cursors,
                                                 rows, gatev, slots);
    fc1_kernel<<<MAXT1 * 16, 256, 0, stream>>>(flat_bf, W1f, eB1, rows, offsets,
                                               tiles1, ntiles, Hbf);
    fc2_kernel<<<MAXT2 * 8, 256, 0, stream>>>(Hbf, W2f, eB2, offsets,
                                              tiles2, ntiles, eo);
    moe_combine_kernel<<<(B_ * O_ / 4) / 256, 256, 0, stream>>>(eo, slots, gatev, moe);
    tower_kernel<<<B_ / 8, 256, 0, stream>>>(moe, tw1, tb1, tw2, tb2, out);
}

// Round 18
// 523.672 us; speedup vs baseline: 1.0342x; 1.0342x over previous
//
#include <hip/hip_runtime.h>
#include <cstdint>

#define B_ 4096
#define N_ 64
#define K_ 48
#define D_ 64
#define F_ 4096
#define E_ 8
#define H_ 1024
#define O_ 512
#define T_ 2
#define TH_ 256
#define NSLOT (B_ * 2)

#define MAXT1 72    // sum over e of ceil(Me/128) <= 64+7

typedef float f32x4 __attribute__((ext_vector_type(4)));
typedef __bf16 bf16x8 __attribute__((ext_vector_type(8)));

__device__ __forceinline__ unsigned short f2bf(float f) {
    union { float f; unsigned int u; } v; v.f = f;
    unsigned int u = v.u;
    u += 0x7FFFu + ((u >> 16) & 1u);   // RNE
    return (unsigned short)(u >> 16);
}

__device__ __forceinline__ void gload_lds16(const void* gptr, void* lptr) {
    auto* g = reinterpret_cast<const __attribute__((address_space(1))) unsigned int*>(
        reinterpret_cast<uintptr_t>(gptr));
    auto* l = reinterpret_cast<__attribute__((address_space(3))) unsigned int*>(
        reinterpret_cast<uintptr_t>(lptr));
    __builtin_amdgcn_global_load_lds(g, l, 16, 0, 0);
}

// ---------------- 0. prefix sums of embW over k, bias folded in ----------------
__global__ __launch_bounds__(64) void prefix_kernel(
    const float* __restrict__ embW, const float* __restrict__ embB,
    float* __restrict__ P)
{
    int n = blockIdx.x;
    int lane = threadIdx.x;
    float acc = embB[n * D_ + lane];
    const float* wsrc = embW + (size_t)n * K_ * D_ + lane;
    float* dst = P + (size_t)n * K_ * D_ + lane;
    #pragma unroll 8
    for (int k = 0; k < K_; ++k) {
        dst[k * D_] = acc;
        acc += wsrc[k * D_];
    }
}

// ---------------- 1. PLE + embedding + gate logits ----------------
__global__ __launch_bounds__(256) void ple_embed_kernel(
    const float* __restrict__ x, const float* __restrict__ plw,
    const float* __restrict__ plb, const float* __restrict__ embW,
    const float* __restrict__ P, const float* __restrict__ gateW,
    unsigned short* __restrict__ flat_bf, float* __restrict__ logits)
{
    __shared__ float gpart[4][E_];
    int b = blockIdx.x;
    int tid = threadIdx.x, lane = tid & 63, w = tid >> 6;

    float xl = x[b * N_ + lane];
    float gp[E_];
    #pragma unroll
    for (int e = 0; e < E_; ++e) gp[e] = 0.0f;

    #pragma unroll 4
    for (int i = 0; i < 16; ++i) {
        int n = w * 16 + i;
        float xn = __shfl(xl, n);
        const float* pw = plw + n * K_;
        const float* pb = plb + n * K_;
        float t = fmaf(pw[0], xn, pb[0]);          // = K*x
        int j = (int)t;
        j = max(0, min(K_ - 1, j));
        float f = fminf(fmaxf(fmaf(pw[j], xn, pb[j]), 0.0f), 1.0f);
        size_t base = ((size_t)n * K_ + j) * D_ + lane;
        float emb = fmaxf(fmaf(f, embW[base], P[base]), 0.0f);
        flat_bf[(size_t)b * F_ + n * D_ + lane] = f2bf(emb);

        const float4* gw4 = (const float4*)(gateW + (size_t)(n * D_ + lane) * E_);
        float4 g0 = gw4[0], g1 = gw4[1];
        gp[0] = fmaf(emb, g0.x, gp[0]);
        gp[1] = fmaf(emb, g0.y, gp[1]);
        gp[2] = fmaf(emb, g0.z, gp[2]);
        gp[3] = fmaf(emb, g0.w, gp[3]);
        gp[4] = fmaf(emb, g1.x, gp[4]);
        gp[5] = fmaf(emb, g1.y, gp[5]);
        gp[6] = fmaf(emb, g1.z, gp[6]);
        gp[7] = fmaf(emb, g1.w, gp[7]);
    }

    #pragma unroll
    for (int off = 32; off > 0; off >>= 1) {
        #pragma unroll
        for (int e = 0; e < E_; ++e) gp[e] += __shfl_down(gp[e], off);
    }
    if (lane == 0) {
        #pragma unroll
        for (int e = 0; e < E_; ++e) gpart[w][e] = gp[e];
    }
    __syncthreads();
    if (tid < E_)
        logits[b * E_ + tid] =
            gpart[0][tid] + gpart[1][tid] + gpart[2][tid] + gpart[3][tid];
}

// ---------------- 2. top-2 gating ----------------
__global__ __launch_bounds__(256) void gate_top2_kernel(
    const float* __restrict__ logits, const float* __restrict__ gate_b,
    int* __restrict__ topi, float* __restrict__ topg, int* __restrict__ counts)
{
    int b = blockIdx.x * 256 + threadIdx.x;
    int lane = threadIdx.x & 63;
    float l[E_];
    #pragma unroll
    for (int e = 0; e < E_; ++e) l[e] = logits[b * E_ + e] + gate_b[e];
    int e1 = 0; float v1 = l[0];
    #pragma unroll
    for (int e = 1; e < E_; ++e) if (l[e] > v1) { v1 = l[e]; e1 = e; }
    int e2 = -1; float v2 = -1e30f;
    #pragma unroll
    for (int e = 0; e < E_; ++e) if (e != e1 && l[e] > v2) { v2 = l[e]; e2 = e; }
    float ex = expf(v2 - v1);
    float g1 = 1.0f / (1.0f + ex);
    float g2 = ex / (1.0f + ex);
    topi[b * 2] = e1; topi[b * 2 + 1] = e2;
    topg[b * 2] = g1; topg[b * 2 + 1] = g2;
    #pragma unroll
    for (int e = 0; e < E_; ++e) {
        unsigned long long m1 = __ballot(e1 == e);
        unsigned long long m2 = __ballot(e2 == e);
        if (lane == 0) {
            int c = __popcll(m1) + __popcll(m2);
            if (c) atomicAdd(&counts[e], c);
        }
    }
}

// ---------------- 3. scan + dense tile table (BM=128, shared by fc1/fc2) --------
__global__ void scan_kernel(const int* __restrict__ counts, int* __restrict__ offsets,
                            int* __restrict__ tiles1, int* __restrict__ ntiles) {
    int e = threadIdx.x;
    if (e >= E_) return;
    int c[E_];
    #pragma unroll
    for (int i = 0; i < E_; ++i) c[i] = counts[i];
    int off = 0, tb = 0, tot = 0, ttot = 0;
    #pragma unroll
    for (int i = 0; i < E_; ++i) {
        int t = (c[i] + 127) >> 7;
        if (i < e) { off += c[i]; tb += t; }
        tot += c[i]; ttot += t;
    }
    offsets[e] = off;
    if (e == 0) { offsets[E_] = tot; ntiles[0] = ttot; }
    int nt = (c[e] + 127) >> 7;
    for (int tr = 0; tr < nt; ++tr) tiles1[tb + tr] = (e << 16) | tr;
}

// ---------------- 4. scatter samples into per-expert slot lists ----------------
// Also records slots[b*2+j] so the tower kernel can gather without atomics.
__global__ __launch_bounds__(256) void scatter_kernel(
    const int* __restrict__ topi, const float* __restrict__ topg,
    const int* __restrict__ offsets, int* __restrict__ cursors,
    int* __restrict__ rows, float* __restrict__ gatev, int* __restrict__ slots)
{
    int b = blockIdx.x * 256 + threadIdx.x;
    int lane = threadIdx.x & 63;
    #pragma unroll
    for (int j = 0; j < 2; ++j) {
        int e = topi[b * 2 + j];
        float g = topg[b * 2 + j];
        #pragma unroll
        for (int ex = 0; ex < E_; ++ex) {
            unsigned long long m = __ballot(e == ex);
            if (e == ex) {
                int leader = __builtin_ctzll(m);
                int base = 0;
                if (lane == leader) base = atomicAdd(&cursors[ex], __popcll(m));
                base = __shfl(base, leader);
                int pos = base + __popcll(m & ((1ull << lane) - 1ull));
                int slot = offsets[ex] + pos;
                rows[slot] = b;
                gatev[slot] = g;
                slots[b * 2 + j] = slot;
            }
        }
    }
}

// ---------------- 5. weights -> MFMA-fragment order, f32 -> bf16 ----------------
// in: (E, R, C) f32 (R = K dim, C = output-col dim)
// out: [e][n0 = C/16][k0 = R/32][lane][8] bf16; a wave's B-fragment load is
// one coalesced 1 KB global_load_dwordx4 (lane-contiguous 16B each).
// Fragment element j of lane: (k = k0*32 + (lane>>4)*8 + j, n = n0*16 + (lane&15)).
__global__ __launch_bounds__(256) void wfrag_kernel(
    const float* __restrict__ in, unsigned short* __restrict__ out, int R, int C)
{
    __shared__ float tile[64][65];
    int e = blockIdx.z;
    int rb = blockIdx.x, cb = blockIdx.y;
    const float* src = in + (size_t)e * R * C + (size_t)(rb * 64) * C + cb * 64;
    int lane = threadIdx.x & 63, w = threadIdx.x >> 6;
    #pragma unroll
    for (int i = 0; i < 16; ++i) {
        int r = w * 16 + i;
        tile[r][lane] = src[(size_t)r * C + lane];
    }
    __syncthreads();
    int NB = C >> 4, KB = R >> 5;
    #pragma unroll
    for (int it = 0; it < 2; ++it) {
        int t = threadIdx.x + it * 256;
        int n0r = t >> 7, k0r = (t >> 6) & 1, ln = t & 63;
        int q = ln >> 4, nl = ln & 15;
        unsigned short v[8];
        #pragma unroll
        for (int j = 0; j < 8; ++j)
            v[j] = f2bf(tile[k0r * 32 + q * 8 + j][n0r * 16 + nl]);
        size_t didx = (((size_t)e * NB + cb * 4 + n0r) * KB + rb * 2 + k0r) * 512
                      + (size_t)ln * 8;
        uint4 pk;
        pk.x = v[0] | ((unsigned)v[1] << 16);
        pk.y = v[2] | ((unsigned)v[3] << 16);
        pk.z = v[4] | ((unsigned)v[5] << 16);
        pk.w = v[6] | ((unsigned)v[7] << 16);
        *(uint4*)&out[didx] = pk;
    }
}

// ---------------- 6. FC1: 128x64 + pipeline + XCD colocation + counted vmcnt ----
__global__ __launch_bounds__(256) void fc1_kernel(
    const unsigned short* __restrict__ Abf,   // flat_bf (B,F)
    const unsigned short* __restrict__ Wf,    // frag layout (E, H/16, F/32, 64, 8)
    const float* __restrict__ bias,           // (E,H)
    const int* __restrict__ rows, const int* __restrict__ offsets,
    const int* __restrict__ tiles1, const int* __restrict__ ntiles,
    unsigned short* __restrict__ Hbf)         // (NSLOT,H) bf16
{
    // bijective decode: bid = tlow + 8*(cn + 16*tgrp); tile = tgrp*8 + tlow
    int bid = blockIdx.x;
    int tlow = bid & 7;
    int rest = bid >> 3;
    int cn   = rest & 15;
    int tile = (rest >> 4) * 8 + tlow;
    if (tile >= ntiles[0]) return;
    int te = tiles1[tile];
    int e = te >> 16, tr = te & 0xffff;
    int m0 = offsets[e], mEnd = offsets[e + 1];
    int Me = mEnd - m0;

    __shared__ alignas(16) unsigned short As[2][128 * 64];   // 32 KB

    int tid = threadIdx.x, lane = tid & 63, wv = tid >> 6;
    int lr = lane >> 3;
    int cg = (lane & 7) ^ lr;     // XOR swizzle -> 2-way-only bank aliasing

    const unsigned short* aptr[4];
    #pragma unroll
    for (int i = 0; i < 4; ++i) {
        int rowA = (wv * 4 + i) * 8 + lr;
        int slot = min(m0 + tr * 128 + rowA, mEnd - 1);
        aptr[i] = Abf + (size_t)rows[slot] * F_ + cg * 8;
    }

    int wvM = wv >> 1, wvN = wv & 1;
    int m16 = lane & 15, q = lane >> 4;

    const unsigned short* bbase[2];
    #pragma unroll
    for (int nt = 0; nt < 2; ++nt) {
        int n0 = cn * 4 + wvN * 2 + nt;
        bbase[nt] = Wf + (((size_t)e * (H_ / 16) + n0) * (F_ / 32)) * 512
                    + (size_t)lane * 8;
    }

    f32x4 zero = {0.f, 0.f, 0.f, 0.f};
    f32x4 acc[4][2];
    #pragma unroll
    for (int i = 0; i < 4; ++i)
        #pragma unroll
        for (int j = 0; j < 2; ++j) acc[i][j] = zero;

#define FC_STAGE(BUF, KK) do {                                              \
    _Pragma("unroll")                                                       \
    for (int i_ = 0; i_ < 4; ++i_)                                          \
        gload_lds16(aptr[i_] + (KK), &As[BUF][(wv * 4 + i_) * 512]);        \
} while (0)

#define FC_LOADB(DST, KK) do {                                              \
    _Pragma("unroll")                                                       \
    for (int nt_ = 0; nt_ < 2; ++nt_)                                       \
        _Pragma("unroll")                                                   \
        for (int ks_ = 0; ks_ < 2; ++ks_)                                   \
            DST[nt_][ks_] = *(const bf16x8*)(bbase[nt_]                     \
                + (size_t)(KK) * 16 + ks_ * 512);                           \
} while (0)

#define FC_COMPUTE(BUF, BF) do {                                            \
    _Pragma("unroll")                                                       \
    for (int ks_ = 0; ks_ < 2; ++ks_) {                                     \
        bf16x8 af_[4];                                                      \
        _Pragma("unroll")                                                   \
        for (int mt_ = 0; mt_ < 4; ++mt_) {                                 \
            int m_ = wvM * 64 + mt_ * 16 + m16;                             \
            int pos_ = (ks_ * 4 + q) ^ (m_ & 7);                            \
            af_[mt_] = *(const bf16x8*)&As[BUF][m_ * 64 + pos_ * 8];        \
        }                                                                   \
        _Pragma("unroll")                                                   \
        for (int mt_ = 0; mt_ < 4; ++mt_)                                   \
            _Pragma("unroll")                                               \
            for (int nt_ = 0; nt_ < 2; ++nt_)                               \
                acc[mt_][nt_] = __builtin_amdgcn_mfma_f32_16x16x32_bf16(    \
                    af_[mt_], BF[nt_][ks_], acc[mt_][nt_], 0, 0, 0);        \
    }                                                                       \
} while (0)

#define FC_WAIT8() asm volatile("s_waitcnt vmcnt(8)" ::: "memory")
#define FC_WAIT0() asm volatile("s_waitcnt vmcnt(0)" ::: "memory")
#define FC_BAR()   __builtin_amdgcn_s_barrier()

    bf16x8 bA[2][2], bB[2][2];
    FC_STAGE(0, 0);
    FC_LOADB(bA, 0);                        // 8 ops in flight

    for (int k0 = 0; k0 < F_; k0 += 128) {
        FC_STAGE(1, k0 + 64);               // +8 -> 16 in flight
        FC_LOADB(bB, k0 + 64);
        FC_WAIT8();                         // oldest 8 done: As[0] written, bA ready
        FC_BAR();                           // all waves' As[0] writes visible
        FC_COMPUTE(0, bA);
        FC_BAR();                           // all reads of As[0] done -> safe to restage

        if (k0 + 128 < F_) {
            FC_STAGE(0, k0 + 128);          // +8 -> 16 in flight
            FC_LOADB(bA, k0 + 128);
            FC_WAIT8();                     // oldest 8 done: As[1] written, bB ready
        } else {
            FC_WAIT0();                     // tail: nothing new issued, drain all
        }
        FC_BAR();
        FC_COMPUTE(1, bB);
        FC_BAR();
    }

    #pragma unroll
    for (int nt = 0; nt < 2; ++nt) {
        int col = cn * 64 + wvN * 32 + nt * 16 + m16;
        float bv = bias[e * H_ + col];
        #pragma unroll
        for (int mt = 0; mt < 4; ++mt) {
            int rbase = tr * 128 + wvM * 64 + mt * 16 + q * 4;
            #pragma unroll
            for (int r = 0; r < 4; ++r) {
                int rr = rbase + r;
                if (rr < Me) {
                    float v = fmaxf(acc[mt][nt][r] + bv, 0.0f);
                    Hbf[(size_t)(m0 + rr) * H_ + col] = f2bf(v);
                }
            }
        }
    }
}

// ---------------- 7. FC2: same structure, atomic-free epilogue ------------------
// Writes raw per-slot expert outputs eo[slot][col] = acc + bias (f32, coalesced).
// Gating + combine happens fused in tower_kernel (no device atomics).
__global__ __launch_bounds__(256) void fc2_kernel(
    const unsigned short* __restrict__ Hbf,   // (NSLOT,H) bf16
    const unsigned short* __restrict__ Wf,    // frag layout (E, O/16, H/32, 64, 8)
    const float* __restrict__ bias,           // (E,O)
    const int* __restrict__ offsets, const int* __restrict__ tiles1,
    const int* __restrict__ ntiles, float* __restrict__ eo)   // (NSLOT,O) f32
{
    // bijective decode: bid = tlow + 8*(cn + 8*tgrp); tile = tgrp*8 + tlow
    int bid = blockIdx.x;
    int tlow = bid & 7;
    int rest = bid >> 3;
    int cn   = rest & 7;
    int tile = (rest >> 3) * 8 + tlow;
    if (tile >= ntiles[0]) return;
    int te = tiles1[tile];
    int e = te >> 16, tr = te & 0xffff;
    int m0 = offsets[e], mEnd = offsets[e + 1];
    int Me = mEnd - m0;

    __shared__ alignas(16) unsigned short As[2][128 * 64];   // 32 KB

    int tid = threadIdx.x, lane = tid & 63, wv = tid >> 6;
    int lr = lane >> 3;
    int cg = (lane & 7) ^ lr;

    const unsigned short* aptr[4];
    #pragma unroll
    for (int i = 0; i < 4; ++i) {
        int rowA = (wv * 4 + i) * 8 + lr;
        int slot = min(m0 + tr * 128 + rowA, mEnd - 1);
        aptr[i] = Hbf + (size_t)slot * H_ + cg * 8;
    }

    int wvM = wv >> 1, wvN = wv & 1;
    int m16 = lane & 15, q = lane >> 4;

    const unsigned short* bbase[2];
    #pragma unroll
    for (int nt = 0; nt < 2; ++nt) {
        int n0 = cn * 4 + wvN * 2 + nt;
        bbase[nt] = Wf + (((size_t)e * (O_ / 16) + n0) * (H_ / 32)) * 512
                    + (size_t)lane * 8;
    }

    f32x4 zero = {0.f, 0.f, 0.f, 0.f};
    f32x4 acc[4][2];
    #pragma unroll
    for (int i = 0; i < 4; ++i)
        #pragma unroll
        for (int j = 0; j < 2; ++j) acc[i][j] = zero;

    bf16x8 bA[2][2], bB[2][2];
    FC_STAGE(0, 0);
    FC_LOADB(bA, 0);

    for (int k0 = 0; k0 < H_; k0 += 128) {
        FC_STAGE(1, k0 + 64);
        FC_LOADB(bB, k0 + 64);
        FC_WAIT8();
        FC_BAR();
        FC_COMPUTE(0, bA);
        FC_BAR();

        if (k0 + 128 < H_) {
            FC_STAGE(0, k0 + 128);
            FC_LOADB(bA, k0 + 128);
            FC_WAIT8();
        } else {
            FC_WAIT0();
        }
        FC_BAR();
        FC_COMPUTE(1, bB);
        FC_BAR();
    }

    #pragma unroll
    for (int nt = 0; nt < 2; ++nt) {
        int col = cn * 64 + wvN * 32 + nt * 16 + m16;
        float bv = bias[e * O_ + col];
        #pragma unroll
        for (int mt = 0; mt < 4; ++mt) {
            int rbase = tr * 128 + wvM * 64 + mt * 16 + q * 4;
            #pragma unroll
            for (int r = 0; r < 4; ++r) {
                int rr = rbase + r;
                if (rr < Me) {
                    eo[(size_t)(m0 + rr) * O_ + col] = acc[mt][nt][r] + bv;
                }
            }
        }
    }
}

#undef FC_STAGE
#undef FC_LOADB
#undef FC_COMPUTE
#undef FC_WAIT8
#undef FC_WAIT0
#undef FC_BAR

// ---------------- 8. fused gated-combine + towers ----------------
// Stages ms[i][c] = g0*eo[s0][c] + g1*eo[s1][c] directly from per-slot expert
// outputs (saves the moe buffer round-trip + one kernel launch). Coalesced
// float4 gathers; slots/gates staged by the first 16 threads.
__global__ __launch_bounds__(256) void tower_kernel(
    const float* __restrict__ eo, const int* __restrict__ slots,
    const float* __restrict__ gatev, const float* __restrict__ tw1,
    const float* __restrict__ tb1, const float* __restrict__ tw2,
    const float* __restrict__ tb2, float* __restrict__ out)
{
    __shared__ float ms[8 * O_];       // 16 KB
    __shared__ float red[16][4];
    __shared__ int   ss[8][2];
    __shared__ float gg[8][2];
    int b0 = blockIdx.x * 8;
    int tid = threadIdx.x, lane = tid & 63, wv = tid >> 6;

    if (tid < 16) {
        int i = tid >> 1, j = tid & 1;
        int sl = slots[(b0 + i) * 2 + j];
        ss[i][j] = sl;
        gg[i][j] = gatev[sl];
    }
    __syncthreads();

    for (int v = tid; v < 8 * (O_ / 4); v += 256) {
        int i = v >> 7;                // O_/4 = 128 float4 per sample
        int c4 = (v & 127) * 4;
        float g0 = gg[i][0], g1 = gg[i][1];
        float4 v0 = *(const float4*)&eo[(size_t)ss[i][0] * O_ + c4];
        float4 v1 = *(const float4*)&eo[(size_t)ss[i][1] * O_ + c4];
        float4 r;
        r.x = g0 * v0.x + g1 * v1.x;
        r.y = g0 * v0.y + g1 * v1.y;
        r.z = g0 * v0.z + g1 * v1.z;
        r.w = g0 * v0.w + g1 * v1.w;
        *(float4*)&ms[i * O_ + c4] = r;
    }
    __syncthreads();

    int s = tid;
    float a0[8], a1[8];
    float bv0 = tb1[s], bv1 = tb1[TH_ + s];
    #pragma unroll
    for (int i = 0; i < 8; ++i) { a0[i] = bv0; a1[i] = bv1; }

    for (int o = 0; o < O_; o += 4) {
        float w0[4], w1[4];
        #pragma unroll
        for (int u = 0; u < 4; ++u) {
            w0[u] = tw1[(size_t)(o + u) * TH_ + s];
            w1[u] = tw1[(size_t)(O_ + o + u) * TH_ + s];
        }
        #pragma unroll
        for (int i = 0; i < 8; ++i) {
            float4 mv = *(const float4*)&ms[i * O_ + o];
            a0[i] = fmaf(mv.x, w0[0], a0[i]);
            a0[i] = fmaf(mv.y, w0[1], a0[i]);
            a0[i] = fmaf(mv.z, w0[2], a0[i]);
            a0[i] = fmaf(mv.w, w0[3], a0[i]);
            a1[i] = fmaf(mv.x, w1[0], a1[i]);
            a1[i] = fmaf(mv.y, w1[1], a1[i]);
            a1[i] = fmaf(mv.z, w1[2], a1[i]);
            a1[i] = fmaf(mv.w, w1[3], a1[i]);
        }
    }

    float w2a = tw2[s], w2b = tw2[TH_ + s];
    #pragma unroll
    for (int i = 0; i < 8; ++i) {
        float p0 = fmaxf(a0[i], 0.0f) * w2a;
        float p1 = fmaxf(a1[i], 0.0f) * w2b;
        #pragma unroll
        for (int off = 32; off > 0; off >>= 1) {
            p0 += __shfl_down(p0, off);
            p1 += __shfl_down(p1, off);
        }
        if (lane == 0) { red[i * 2 + 0][wv] = p0; red[i * 2 + 1][wv] = p1; }
    }
    __syncthreads();
    if (tid < 16) {
        int i = tid >> 1, t = tid & 1;
        float v = red[tid][0] + red[tid][1] + red[tid][2] + red[tid][3] + tb2[t];
        out[(size_t)(b0 + i) * T_ + t] = v;
    }
}

extern "C" void kernel_launch(void* const* d_in, const int* in_sizes, int n_in,
                              void* d_out, int out_size, void* d_ws, size_t ws_size,
                              hipStream_t stream)
{
    const float* x     = (const float*)d_in[0];
    const float* plw   = (const float*)d_in[1];
    const float* plb   = (const float*)d_in[2];
    const float* embW  = (const float*)d_in[3];
    const float* embB  = (const float*)d_in[4];
    const float* gateW = (const float*)d_in[5];
    const float* gateB = (const float*)d_in[6];
    const float* eW1   = (const float*)d_in[7];
    const float* eB1   = (const float*)d_in[8];
    const float* eW2   = (const float*)d_in[9];
    const float* eB2   = (const float*)d_in[10];
    const float* tw1   = (const float*)d_in[11];
    const float* tb1   = (const float*)d_in[12];
    const float* tw2   = (const float*)d_in[13];
    const float* tb2   = (const float*)d_in[14];
    float* out = (float*)d_out;

    char* w = (char*)d_ws;
    auto alloc = [&](size_t bytes) {
        char* p = w; w += (bytes + 255) & ~(size_t)255; return p;
    };
    unsigned short* flat_bf = (unsigned short*)alloc((size_t)B_ * F_ * 2);      // 33.6 MB
    unsigned short* W1f     = (unsigned short*)alloc((size_t)E_ * H_ * F_ * 2); // 67.1 MB
    unsigned short* W2f     = (unsigned short*)alloc((size_t)E_ * O_ * H_ * 2); //  8.4 MB
    unsigned short* Hbf     = (unsigned short*)alloc((size_t)NSLOT * H_ * 2);   // 16.8 MB
    float* eo      = (float*)alloc((size_t)NSLOT * O_ * 4);                     // 16.8 MB
    float* Ppre    = (float*)alloc((size_t)N_ * K_ * D_ * 4);                   // 786 KB
    float* logits  = (float*)alloc((size_t)B_ * E_ * 4);
    int*   topi    = (int*)alloc((size_t)B_ * 2 * 4);
    float* topg    = (float*)alloc((size_t)B_ * 2 * 4);
    int*   rows    = (int*)alloc((size_t)NSLOT * 4);
    float* gatev   = (float*)alloc((size_t)NSLOT * 4);
    int*   slots   = (int*)alloc((size_t)B_ * 2 * 4);
    int*   counts  = (int*)alloc(E_ * 4);
    int*   offsets = (int*)alloc((E_ + 1) * 4);
    int*   cursors = (int*)alloc(E_ * 4);
    int*   tiles1  = (int*)alloc(MAXT1 * 4);
    int*   ntiles  = (int*)alloc(2 * 4);

    hipMemsetAsync(counts, 0, E_ * 4, stream);
    hipMemsetAsync(cursors, 0, E_ * 4, stream);

    prefix_kernel<<<N_, 64, 0, stream>>>(embW, embB, Ppre);
    ple_embed_kernel<<<B_, 256, 0, stream>>>(x, plw, plb, embW, Ppre, gateW,
                                             flat_bf, logits);
    wfrag_kernel<<<dim3(F_ / 64, H_ / 64, E_), 256, 0, stream>>>(eW1, W1f, F_, H_);
    wfrag_kernel<<<dim3(H_ / 64, O_ / 64, E_), 256, 0, stream>>>(eW2, W2f, H_, O_);
    gate_top2_kernel<<<B_ / 256, 256, 0, stream>>>(logits, gateB, topi, topg, counts);
    scan_kernel<<<1, 64, 0, stream>>>(counts, offsets, tiles1, ntiles);
    scatter_kernel<<<B_ / 256, 256, 0, stream>>>(topi, topg, offsets, cursors,
                                                 rows, gatev, slots);
    fc1_kernel<<<MAXT1 * 16, 256, 0, stream>>>(flat_bf, W1f, eB1, rows, offsets,
                                               tiles1, ntiles, Hbf);
    fc2_kernel<<<MAXT1 * 8, 256, 0, stream>>>(Hbf, W2f, eB2, offsets,
                                              tiles1, ntiles, eo);
    tower_kernel<<<B_ / 8, 256, 0, stream>>>(eo, slots, gatev, tw1, tb1, tw2, tb2, out);
}